// Round 5
// baseline (219.300 us; speedup 1.0000x reference)
//
#include <hip/hip_runtime.h>

// out[b,c,i,j] = x[b,c,i,j] * (i%3!=0) * (j%3!=0)
// Unfold->fold composite == elementwise separable 0/1 mask (see prior rounds).
//
// R4 experiment: R1 structure EXACTLY, but with the nontemporal hints
// REMOVED (plain cached loads/stores).
// Evidence: R1 (222 MB) = 209.1, R3 dense (268 MB) = 217.3 -> marginal BW of
// the extra traffic ~5.6 TB/s, fixed window overhead ~169.5 us in both.
// So the kernel streams at ~5.6 TB/s regardless of raggedness/divergence,
// while a plain float4 D2D copy measures 6.29 TB/s and the harness fills hit
// 6.7 TB/s. The one structural difference left vs a plain copy is the NT
// hint on every load/store; NT bypasses normal L2 allocation and can degrade
// TCC coalescing/write-combining. There is no reuse to protect (the 512 MiB
// poison fill evicts caches every iteration), so NT buys nothing -> A/B it.
//
// Structure (R1, best measured): one float4 per thread, linear sweep, grid
// exact. Rows with i%3==0 (11/32): store zeros, skip the load (rows are
// 128B-aligned segments, so skipped rows cost no HBM fetch).

typedef float vf4 __attribute__((ext_vector_type(4)));

constexpr int N_TOTAL = 64 * 512 * 32 * 32;   // 33,554,432 floats
constexpr int N_F4    = N_TOTAL / 4;          // 8,388,608 float4s

__global__ __launch_bounds__(256) void unfoldfold_mask_kernel(
    const vf4* __restrict__ x, vf4* __restrict__ out) {
    int q = blockIdx.x * blockDim.x + threadIdx.x;   // float4 index; grid exact
    int i = (q >> 3) & 31;                           // row within 32x32 image
    if ((i % 3) == 0) {
        out[q] = (vf4)(0.f);
        return;
    }
    vf4 a = x[q];
    // j0 = (q&7)*4; element e (j=j0+e) zeroed iff (j0+e)%3==0; m = (q&7)%3
    int m = (q & 7) % 3;
    if (m == 0)      { a.x = 0.f; a.w = 0.f; }   // e=0,3
    else if (m == 1) { a.z = 0.f; }              // e=2
    else             { a.y = 0.f; }              // e=1
    out[q] = a;
}

extern "C" void kernel_launch(void* const* d_in, const int* in_sizes, int n_in,
                              void* d_out, int out_size, void* d_ws, size_t ws_size,
                              hipStream_t stream) {
    const vf4* x = (const vf4*)d_in[0];
    vf4* out = (vf4*)d_out;
    unfoldfold_mask_kernel<<<N_F4 / 256, 256, 0, stream>>>(x, out);
}

// Round 6
// 209.611 us; speedup vs baseline: 1.0462x; 1.0462x over previous
//
#include <hip/hip_runtime.h>

// out[b,c,i,j] = x[b,c,i,j] * (i%3!=0) * (j%3!=0)
// Unfold->fold composite == elementwise separable 0/1 mask: the fold
// scatter-add targets exactly the coords the unfold read, so the composite
// is elementwise; zero iff (idx+PAD)%3==1, i.e. idx%3==0, separably in i,j.
//
// FINAL (revert to best-measured, R1/R2 structure):
//  - One float4 per thread, linear sweep, grid exact. Lanes dense within
//    each wave instruction (1 KB/instr) — minimal L1/L2 transactions.
//  - Rows with i%3==0 (11/32): store zeros, skip the load. Rows are
//    128B-aligned segments, so skipped rows cost no HBM fetch (read stream
//    88 MB instead of 134 MB; write 134 MB mandatory).
//  - Non-temporal load/store: A/B'd in R4 — removing NT cost ~4 us (plain
//    write-allocate churns L2/L3 for write-once lines). Keep NT.
// Measured plateau: ~5.6 TB/s mixed-stream (fills prove 6.7 TB/s pure-write;
// MLP/divergence/raggedness variants all tested, all within noise or worse).

typedef float vf4 __attribute__((ext_vector_type(4)));

constexpr int N_TOTAL = 64 * 512 * 32 * 32;   // 33,554,432 floats
constexpr int N_F4    = N_TOTAL / 4;          // 8,388,608 float4s

__global__ __launch_bounds__(256) void unfoldfold_mask_kernel(
    const vf4* __restrict__ x, vf4* __restrict__ out) {
    int q = blockIdx.x * blockDim.x + threadIdx.x;   // float4 index; grid exact
    int i = (q >> 3) & 31;                           // row within 32x32 image
    if ((i % 3) == 0) {
        vf4 z = (vf4)(0.f);
        __builtin_nontemporal_store(z, &out[q]);
        return;
    }
    vf4 a = __builtin_nontemporal_load(&x[q]);
    // j0 = (q&7)*4; element e (j=j0+e) zeroed iff (j0+e)%3==0; m = (q&7)%3
    int m = (q & 7) % 3;
    if (m == 0)      { a.x = 0.f; a.w = 0.f; }   // e=0,3
    else if (m == 1) { a.z = 0.f; }              // e=2
    else             { a.y = 0.f; }              // e=1
    __builtin_nontemporal_store(a, &out[q]);
}

extern "C" void kernel_launch(void* const* d_in, const int* in_sizes, int n_in,
                              void* d_out, int out_size, void* d_ws, size_t ws_size,
                              hipStream_t stream) {
    const vf4* x = (const vf4*)d_in[0];
    vf4* out = (vf4*)d_out;
    unfoldfold_mask_kernel<<<N_F4 / 256, 256, 0, stream>>>(x, out);
}